// Round 7
// baseline (33.113 us; speedup 1.0000x reference)
//
#include <hip/hip_runtime.h>
#include <math.h>

#define NQ 12
#define NN 4096   // 2^12

typedef float f2 __attribute__((ext_vector_type(2)));  // (re, im) in a VGPR pair

__device__ __forceinline__ float2 cmulh(float2 a, float2 b) {
    return make_float2(a.x * b.x - a.y * b.y, a.x * b.y + a.y * b.x);
}

// ---- packed complex arithmetic: 2 x v_pk_fma_f32 per complex MAC ----
// m = [mr, mi] (VGPR pair, wave-uniform from LDS broadcast), b = [br, bi].
__device__ __forceinline__ void cmac_pk(f2& acc, f2 m, f2 b) {
    asm("v_pk_fma_f32 %0, %1, %2, %0 op_sel:[0,0,0] op_sel_hi:[0,1,1]\n\t"
        "v_pk_fma_f32 %0, %1, %2, %0 op_sel:[1,1,0] op_sel_hi:[1,0,1] neg_lo:[1,0,0]"
        : "+v"(acc) : "v"(m), "v"(b));
}
__device__ __forceinline__ void cmul_pk(f2& r, f2 m, f2 b) {
    asm("v_pk_mul_f32 %0, %1, %2 op_sel:[0,0] op_sel_hi:[0,1]\n\t"
        "v_pk_fma_f32 %0, %1, %2, %0 op_sel:[1,1,0] op_sel_hi:[1,0,1] neg_lo:[1,0,0]"
        : "=&v"(r) : "v"(m), "v"(b));
}

// Radix-2 butterfly on slot bit log2(D) over 8 slots.
template<int D>
__device__ __forceinline__ void stagepk8(f2 (&v)[8], f2 m00, f2 m01, f2 m10, f2 m11) {
    #pragma unroll
    for (int s = 0; s < 8; ++s) {
        if (s & D) continue;
        f2 va = v[s], vb = v[s | D];
        f2 r0, r1;
        cmul_pk(r0, m00, va); cmac_pk(r0, m01, vb);
        cmul_pk(r1, m10, va); cmac_pk(r1, m11, vb);
        v[s] = r0; v[s | D] = r1;
    }
}

// 512 threads/block, TWO batch rows per block (grid = B/2 = 1024, fully
// resident at 4 blocks/CU), 8 complex elements/thread. Single kernel: the
// 12 per-bit 2x2 matrices are computed by threads 0..11 into Msh (one
// barrier), then read via broadcast ds_read_b64 at each stage.
// M_p = diag(e^{i phi},1) * u * diag(e^{i theta},1) * u * diag(e^{i a}, e^{i b}),
// u = (1/sqrt2)[[1,i],[i,1]], parameter index q = 11-p.
//
// Mappings (T = thread 9 bits, s = slot 3 bits):
//   A: i = T<<3 | s                         -> slot bits {0,1,2}
//   B: i = (T>>3)<<6 | s<<3 | (T&7)         -> slot bits {3,4,5}
//   C: i = (T>>6)<<9 | s<<6 | (T&63)        -> slot bits {6,7,8}
//   D: i = s<<9 | T                         -> slot bits {9,10,11}
// LDS layout: idx(i) = i + (i>>3) (stride-9/8 padding; 4608 f2 = 36 KB).
// A, B, C all keep i[11:9] == T[8:6] (the wave id) -> transposes A->B, B->C
// and the C-side write of C->D are wave-region-local (in-order DS pipe, no
// barrier). Only the D-read crosses waves -> barrier before it, and a second
// barrier after it (row 0 only) so row 1's A-writes can't race D-reads.
// Both rows' global loads are issued at the very top (before any unpack) so
// the full read burst is in flight while Msh is computed. Stores are
// non-temporal: output is never re-read; no-allocate keeps x L3-resident.
__global__ __launch_bounds__(512, 8) void sq_layer(const float* __restrict__ x,
                                                   float* __restrict__ out,
                                                   const float* __restrict__ alphas,
                                                   const float* __restrict__ betas,
                                                   const float* __restrict__ thetas,
                                                   const float* __restrict__ phis) {
    __shared__ f2 lds[4608];  // 36 KB
    __shared__ f2 Msh[48];
    const int T = threadIdx.x;
    const size_t row0 = (size_t)blockIdx.x * 2;

    // ---- issue ALL global loads (both rows) first ----
    const float* px = x + row0 * (2 * NN) + (T << 3);
    float4 ra0 = *reinterpret_cast<const float4*>(px);
    float4 rb0 = *reinterpret_cast<const float4*>(px + 4);
    float4 ia0 = *reinterpret_cast<const float4*>(px + NN);
    float4 ib0 = *reinterpret_cast<const float4*>(px + NN + 4);
    float4 ra1 = *reinterpret_cast<const float4*>(px + 2 * NN);
    float4 rb1 = *reinterpret_cast<const float4*>(px + 2 * NN + 4);
    float4 ia1 = *reinterpret_cast<const float4*>(px + 3 * NN);
    float4 ib1 = *reinterpret_cast<const float4*>(px + 3 * NN + 4);

    // ---- per-block matrix setup (hides under the load burst) ----
    if (T < NQ) {
        int p = T, q = NQ - 1 - p;
        float sa, ca, sb, cb, st, ct, sf, cf;
        sincosf(alphas[q], &sa, &ca);
        sincosf(betas[q],  &sb, &cb);
        sincosf(thetas[q], &st, &ct);
        sincosf(phis[q],   &sf, &cf);
        float2 A  = make_float2(ca, sa);
        float2 Bb = make_float2(cb, sb);
        float2 F  = make_float2(cf, sf);
        float2 Tm  = make_float2(0.5f * (ct - 1.0f), 0.5f * st);  // (T-1)/2
        float2 Tp  = make_float2(0.5f * (ct + 1.0f), 0.5f * st);  // (T+1)/2
        float2 iTp = make_float2(-Tp.y, Tp.x);                    // i*(T+1)/2
        float2 m00 = cmulh(cmulh(F, Tm), A);
        float2 m01 = cmulh(cmulh(F, iTp), Bb);
        float2 m10 = cmulh(iTp, A);
        float2 m11 = cmulh(make_float2(-Tm.x, -Tm.y), Bb);
        Msh[p * 4 + 0] = f2{m00.x, m00.y};
        Msh[p * 4 + 1] = f2{m01.x, m01.y};
        Msh[p * 4 + 2] = f2{m10.x, m10.y};
        Msh[p * 4 + 3] = f2{m11.x, m11.y};
    }
    __syncthreads();  // Msh ready

    #pragma unroll
    for (int r = 0; r < 2; ++r) {
        f2 v[8];
        float4 ra = (r == 0) ? ra0 : ra1;
        float4 rb = (r == 0) ? rb0 : rb1;
        float4 ia = (r == 0) ? ia0 : ia1;
        float4 ib = (r == 0) ? ib0 : ib1;
        v[0] = f2{ra.x, ia.x}; v[1] = f2{ra.y, ia.y};
        v[2] = f2{ra.z, ia.z}; v[3] = f2{ra.w, ia.w};
        v[4] = f2{rb.x, ib.x}; v[5] = f2{rb.y, ib.y};
        v[6] = f2{rb.z, ib.z}; v[7] = f2{rb.w, ib.w};

        // ---- phase 1: bits 0,1,2 ----
        stagepk8<1>(v, Msh[0],  Msh[1],  Msh[2],  Msh[3]);
        stagepk8<2>(v, Msh[4],  Msh[5],  Msh[6],  Msh[7]);
        stagepk8<4>(v, Msh[8],  Msh[9],  Msh[10], Msh[11]);

        // ---- transpose A -> B (wave-region-local, no barrier) ----
        {
            f2* wp = lds + 9 * T;
            #pragma unroll
            for (int s = 0; s < 8; ++s) wp[s] = v[s];
        }
        {
            const f2* rp = lds + 72 * (T >> 3) + (T & 7);
            #pragma unroll
            for (int s = 0; s < 8; ++s) v[s] = rp[9 * s];
        }

        // ---- phase 2: bits 3,4,5 ----
        stagepk8<1>(v, Msh[12], Msh[13], Msh[14], Msh[15]);
        stagepk8<2>(v, Msh[16], Msh[17], Msh[18], Msh[19]);
        stagepk8<4>(v, Msh[20], Msh[21], Msh[22], Msh[23]);

        // ---- transpose B -> C (wave-region-local, no barrier) ----
        {
            f2* wp = lds + 72 * (T >> 3) + (T & 7);
            #pragma unroll
            for (int s = 0; s < 8; ++s) wp[9 * s] = v[s];
        }
        {
            const f2* rp = lds + 576 * (T >> 6) + (T & 63) + ((T & 63) >> 3);
            #pragma unroll
            for (int s = 0; s < 8; ++s) v[s] = rp[72 * s];
        }

        // ---- phase 3: bits 6,7,8 ----
        stagepk8<1>(v, Msh[24], Msh[25], Msh[26], Msh[27]);
        stagepk8<2>(v, Msh[28], Msh[29], Msh[30], Msh[31]);
        stagepk8<4>(v, Msh[32], Msh[33], Msh[34], Msh[35]);

        // ---- transpose C -> D: write C (own region), BARRIER, read D ----
        {
            f2* wp = lds + 576 * (T >> 6) + (T & 63) + ((T & 63) >> 3);
            #pragma unroll
            for (int s = 0; s < 8; ++s) wp[72 * s] = v[s];
        }
        __syncthreads();
        {
            const f2* rp = lds + T + (T >> 3);   // idx(s<<9 | T) = 576s + T + (T>>3)
            #pragma unroll
            for (int s = 0; s < 8; ++s) v[s] = rp[576 * s];
        }
        if (r == 0) __syncthreads();  // D-reads done before row 1's A-writes

        // ---- phase 4: bits 9,10,11 ----
        stagepk8<1>(v, Msh[36], Msh[37], Msh[38], Msh[39]);
        stagepk8<2>(v, Msh[40], Msh[41], Msh[42], Msh[43]);
        stagepk8<4>(v, Msh[44], Msh[45], Msh[46], Msh[47]);

        // ---- store (mapping D): i = s<<9 | T, wave-contiguous, non-temporal ----
        {
            float* po = out + (row0 + r) * (2 * NN);
            #pragma unroll
            for (int s = 0; s < 8; ++s) {
                int i = (s << 9) | T;
                __builtin_nontemporal_store(v[s].x, po + i);
                __builtin_nontemporal_store(v[s].y, po + NN + i);
            }
        }
    }
}

extern "C" void kernel_launch(void* const* d_in, const int* in_sizes, int n_in,
                              void* d_out, int out_size, void* d_ws, size_t ws_size,
                              hipStream_t stream) {
    const float* x      = (const float*)d_in[0];
    const float* alphas = (const float*)d_in[1];
    const float* betas  = (const float*)d_in[2];
    const float* thetas = (const float*)d_in[3];
    const float* phis   = (const float*)d_in[4];
    float* out = (float*)d_out;

    const int B = in_sizes[0] / (2 * NN);  // 2048

    hipLaunchKernelGGL(sq_layer, dim3(B / 2), dim3(512), 0, stream,
                       x, out, alphas, betas, thetas, phis);
}